// Round 1
// 245.472 us; speedup vs baseline: 1.2377x; 1.2377x over previous
//
#include <hip/hip_runtime.h>

#define BB 4
#define PP 2048
#define CCLUS 512
#define DD 1024
#define HH 16
#define DHH 64

typedef __attribute__((ext_vector_type(8))) short short8;
typedef __attribute__((ext_vector_type(4))) float floatx4;
typedef unsigned short u16;
typedef unsigned int u32;
typedef unsigned long long u64;

__device__ __forceinline__ float bf2f(u16 u) {
  union { u32 i; float f; } v; v.i = ((u32)u) << 16; return v.f;
}
__device__ __forceinline__ u16 f2bf(float f) {
  union { float f; u32 i; } v; v.f = f;
  u32 x = v.i;
  return (u16)((x + 0x7fffu + ((x >> 16) & 1u)) >> 16);  // RNE
}
__device__ __forceinline__ u64 pack4(float a, float b, float c, float d) {
  return (u64)f2bf(a) | ((u64)f2bf(b) << 16) | ((u64)f2bf(c) << 32) | ((u64)f2bf(d) << 48);
}

__device__ __forceinline__ floatx4 mfma16(short8 a, short8 b, floatx4 c) {
  return __builtin_amdgcn_mfma_f32_16x16x32_bf16(a, b, c, 0, 0, 0);
}

// async global->LDS, 16B/lane; LDS dest = wave-uniform base + lane*16 (m97)
__device__ __forceinline__ void gload_lds16(const u16* g, u16* l) {
  __builtin_amdgcn_global_load_lds(
      (const __attribute__((address_space(1))) u32*)g,
      (__attribute__((address_space(3))) u32*)l, 16, 0, 0);
}

// ---------------- f32 -> bf16 cast for para & cluster ----------------
__global__ __launch_bounds__(256) void cast_k(
    const float* __restrict__ para, const float* __restrict__ cluster,
    u16* __restrict__ Ap, u16* __restrict__ Ac) {
  const int NP4 = (BB * PP * DD) / 4;
  const int NC4 = (BB * CCLUS * DD) / 4;
  const int stride = gridDim.x * blockDim.x;
  for (int i = blockIdx.x * blockDim.x + threadIdx.x; i < NP4 + NC4; i += stride) {
    const float* src; u16* dst; int j;
    if (i < NP4) { src = para; dst = Ap; j = i; }
    else         { src = cluster; dst = Ac; j = i - NP4; }
    const float4 v = *(const float4*)(src + (size_t)j * 4);
    *(u64*)(dst + (size_t)j * 4) = pack4(v.x, v.y, v.z, v.w);
  }
}

// ---------------- transpose+cast Wq/Wk/Wv (1024x1024 f32 -> bf16^T) ----------------
__global__ __launch_bounds__(1024) void transpose3_k(
    const float* __restrict__ Wq, const float* __restrict__ Wk, const float* __restrict__ Wv,
    u16* __restrict__ WqT, u16* __restrict__ WkT, u16* __restrict__ WvT) {
  __shared__ u16 tile[32][33];
  const int z = blockIdx.z;
  const float* src = (z == 0) ? Wq : (z == 1) ? Wk : Wv;
  u16* dst = (z == 0) ? WqT : (z == 1) ? WkT : WvT;
  int x = blockIdx.x * 32 + threadIdx.x;
  int y = blockIdx.y * 32 + threadIdx.y;
  tile[threadIdx.y][threadIdx.x] = f2bf(src[y * DD + x]);
  __syncthreads();
  x = blockIdx.y * 32 + threadIdx.x;
  y = blockIdx.x * 32 + threadIdx.y;
  dst[y * DD + x] = tile[threadIdx.x][threadIdx.y];
}

// ---------------- fused QKV GEMM (m97 global_load_lds staging) ----------------
// Q -> Qb[b*P+p][1024] (scaled by 1/8)
// K -> Kp[b][h][c][64]    (per-head row-major, 128B rows)
// V -> Vt[b][h][d][512]   (per-head TRANSPOSED, 1KB rows)
// packed grid.x=96: [0,64)=Q, [64,80)=K, [80,96)=V.
__global__ __launch_bounds__(256) void qkv_gemm3(
    const u16* __restrict__ Ap, const u16* __restrict__ Ac,
    const u16* __restrict__ WqT, const u16* __restrict__ WkT, const u16* __restrict__ WvT,
    const float* __restrict__ bq, const float* __restrict__ bk, const float* __restrict__ bv,
    u16* __restrict__ Qb, u16* __restrict__ Kp, u16* __restrict__ Vt) {
  const int bx = blockIdx.x;
  const u16* A; const u16* BT; const float* bias; int mt, mode;
  if (bx < 64)      { A = Ap; BT = WqT; bias = bq; mt = bx;      mode = 0; }
  else if (bx < 80) { A = Ac; BT = WkT; bias = bk; mt = bx - 64; mode = 1; }
  else              { A = Ac; BT = WvT; bias = bv; mt = bx - 80; mode = 2; }

  __shared__ __align__(16) u16 As[128 * 32];
  __shared__ __align__(16) u16 Bs[128 * 32];

  const int tid = threadIdx.x;
  const int w = tid >> 6, lane = tid & 63, quad = lane >> 4, cidx = lane & 15;
  const int wy = w >> 1, wx = w & 1;
  const int m0 = mt * 128, n0 = blockIdx.y * 128;

  floatx4 acc[4][4];
#pragma unroll
  for (int i = 0; i < 4; i++)
#pragma unroll
    for (int j = 0; j < 4; j++) acc[i][j] = (floatx4){0.f, 0.f, 0.f, 0.f};

  const int row0 = tid >> 2, kc0 = tid & 3;
  const int offG0 = row0 * 1024 + kc0 * 8;
  const int offG1 = (row0 + 64) * 1024 + kc0 * 8;
  u16* ldsA0 = As + (size_t)(w * 64) * 8;
  u16* ldsA1 = As + (size_t)(w * 64 + 256) * 8;
  u16* ldsB0 = Bs + (size_t)(w * 64) * 8;
  u16* ldsB1 = Bs + (size_t)(w * 64 + 256) * 8;

  const u16* Abase = A + (size_t)m0 * 1024;
  const u16* Bbase = BT + (size_t)n0 * 1024;

  for (int kt = 0; kt < 32; kt++) {
    const u16* Ak = Abase + kt * 32;
    const u16* Bk = Bbase + kt * 32;
    gload_lds16(Ak + offG0, ldsA0);
    gload_lds16(Ak + offG1, ldsA1);
    gload_lds16(Bk + offG0, ldsB0);
    gload_lds16(Bk + offG1, ldsB1);
    __syncthreads();

    short8 af[4], bfr[4];
#pragma unroll
    for (int i = 0; i < 4; i++) {
      int ra = wy * 64 + i * 16 + cidx;
      af[i] = *(const short8*)&As[ra * 32 + quad * 8];
      int rb = wx * 64 + i * 16 + cidx;
      bfr[i] = *(const short8*)&Bs[rb * 32 + quad * 8];
    }
#pragma unroll
    for (int mi = 0; mi < 4; mi++)
#pragma unroll
      for (int ni = 0; ni < 4; ni++)
        acc[mi][ni] = mfma16(af[mi], bfr[ni], acc[mi][ni]);
    __syncthreads();
  }

#pragma unroll
  for (int ni = 0; ni < 4; ni++) {
    const int ncol = n0 + wx * 64 + ni * 16 + cidx;
    const float bvv = bias[ncol];
    const int h = ncol >> 6, dh = ncol & 63;
#pragma unroll
    for (int mi = 0; mi < 4; mi++) {
      const int mrow = m0 + wy * 64 + mi * 16 + quad * 4;
      if (mode == 0) {
#pragma unroll
        for (int r = 0; r < 4; r++) {
          float v = (acc[mi][ni][r] + bvv) * 0.125f;
          Qb[(size_t)(mrow + r) * 1024 + ncol] = f2bf(v);
        }
      } else if (mode == 1) {
        // rows of Ac are b*512 + c
#pragma unroll
        for (int r = 0; r < 4; r++) {
          const int row = mrow + r;
          const int bb = row >> 9, c = row & 511;
          Kp[((size_t)(bb * HH + h) * CCLUS + c) * DHH + dh] = f2bf(acc[mi][ni][r] + bvv);
        }
      } else {
        const int bb = mrow >> 9, c0 = mrow & 511;  // r=0..3 stays in same b
        *(u64*)&Vt[((size_t)(bb * HH + h) * DHH + dh) * CCLUS + c0] =
            pack4(acc[mi][ni][0] + bvv, acc[mi][ni][1] + bvv,
                  acc[mi][ni][2] + bvv, acc[mi][ni][3] + bvv);
      }
    }
  }
}

// ---------------- fused masked attention v4 ----------------
// 8 waves x 512 threads; block = 128 p-rows, wave = 16 p-rows.
// Per 64-c chunk: K[64c][64d] and V^T[64d][64c] staged via coalesced
// global_load_lds into double-buffered, XOR-swizzled LDS (T2+T3-min).
// S^T = K·Q^T per 16-c tile; unnormalized E=edge*exp(s) through PV;
// oacc scaled by 1/srow at the end.
__global__ __launch_bounds__(512, 5) void attn_k4(
    const u16* __restrict__ Qb, const u16* __restrict__ Kp, const u16* __restrict__ Vt,
    const float* __restrict__ edge, float* __restrict__ ctx) {
  const int b = blockIdx.z, h = blockIdx.y, p0 = blockIdx.x * 128;
  const int tid = threadIdx.x;
  const int w = tid >> 6, lane = tid & 63, quad = lane >> 4, cidx = lane & 15;

  __shared__ __align__(16) u16 Ks[2][64 * 64];      // [c][d] swizzled, 8KB each
  __shared__ __align__(16) u16 Vs[2][64 * 64];      // [d][c] swizzled, 8KB each
  __shared__ __align__(16) u16 attnS[8][16][72];    // per-wave [p][c-local], padded

  const u16* __restrict__ Kbh = Kp + (size_t)(b * HH + h) * CCLUS * DHH;
  const u16* __restrict__ Vbh = Vt + (size_t)(b * HH + h) * DHH * CCLUS;

  // Q frags (B-operand: n=cidx -> p row, k=quad*8+j), loaded once
  const int prow = p0 + w * 16 + cidx;
  const u16* qg = Qb + (size_t)(b * PP + prow) * DD + h * DHH + quad * 8;
  const short8 qf0 = *(const short8*)qg;
  const short8 qf1 = *(const short8*)(qg + 32);
  const float* Erow = edge + (size_t)(b * PP + prow) * CCLUS;

  float srow = 0.f;
  floatx4 oacc[4];
#pragma unroll
  for (int nt = 0; nt < 4; nt++) oacc[nt] = (floatx4){0.f, 0.f, 0.f, 0.f};

  // staging geometry: slot=tid (512 slots x 16B = one 8KB buffer)
  const int srow_i = tid >> 3;                        // row 0..63
  const int sc = ((tid & 7) ^ (srow_i & 7)) << 3;     // inverse-swizzled src col (u16)
  const int ldsoff = w * 64 * 8;                      // wave window (u16)

  auto STAGE = [&](int cc, int bufi) {
    const u16* kg = Kbh + (size_t)cc * 64 * DHH;
    const u16* vg = Vbh + cc * 64;
    gload_lds16(kg + (size_t)srow_i * DHH + sc, &Ks[bufi][ldsoff]);
    gload_lds16(vg + (size_t)srow_i * CCLUS + sc, &Vs[bufi][ldsoff]);
  };

  STAGE(0, 0);
  __syncthreads();

  const int swz = (cidx & 7) << 3;  // read-side XOR (u16 units), row&7 == cidx&7

  for (int cc = 0; cc < 8; cc++) {
    const int bufi = cc & 1;
    if (cc < 7) STAGE(cc + 1, bufi ^ 1);  // async prefetch into other buffer
    const u16* __restrict__ KsB = &Ks[bufi][0];
    const u16* __restrict__ VsB = &Vs[bufi][0];

#pragma unroll
    for (int t = 0; t < 4; t++) {
      const int krow = (t * 16 + cidx) * 64;
      const short8 kf0 = *(const short8*)&KsB[krow + ((quad * 8) ^ swz)];
      const short8 kf1 = *(const short8*)&KsB[krow + ((32 + quad * 8) ^ swz)];
      floatx4 s4 = (floatx4){0.f, 0.f, 0.f, 0.f};
      s4 = mfma16(kf0, qf0, s4);
      s4 = mfma16(kf1, qf1, s4);
      // lane owns S^T[c = cc*64+t*16+quad*4+r][p = prow]
      const int ce = cc * 64 + t * 16 + quad * 4;
      const float4 e4 = *(const float4*)(Erow + ce);
      float E[4];
#pragma unroll
      for (int r = 0; r < 4; r++) {
        const float e = (&e4.x)[r];
        const float sv = s4[r];
        const float ex = (e > 0.f && sv == sv) ? __expf(fminf(sv, 15.f)) : 0.f;
        srow += ex;
        E[r] = ex * e;
      }
      *(u64*)&attnS[w][cidx][t * 16 + quad * 4] = pack4(E[0], E[1], E[2], E[3]);
    }
    // PV: A = attnS[p=cidx][c=ks*32+quad*8+j], B = V^T from swizzled LDS
#pragma unroll
    for (int ks = 0; ks < 2; ks++) {
      const short8 afr = *(const short8*)&attnS[w][cidx][ks * 32 + quad * 8];
#pragma unroll
      for (int nt = 0; nt < 4; nt++) {
        const short8 bfr =
            *(const short8*)&VsB[(nt * 16 + cidx) * 64 + ((ks * 32 + quad * 8) ^ swz)];
        oacc[nt] = mfma16(afr, bfr, oacc[nt]);
      }
    }
    __syncthreads();  // drains prefetch (vmcnt) + protects buffer reuse
  }

  // reduce srow across quads (lane^16, lane^32 hold same p, disjoint c)
  srow += __shfl_xor(srow, 16, 64);
  srow += __shfl_xor(srow, 32, 64);
  const float sinv = (srow > 0.f) ? 1.0f / srow : 0.f;

#pragma unroll
  for (int r = 0; r < 4; r++) {
    const float sv = __shfl(sinv, quad * 4 + r, 16);  // sinv of p-local quad*4+r
#pragma unroll
    for (int nt = 0; nt < 4; nt++) {
      const size_t off =
          (size_t)(b * PP + p0 + w * 16 + quad * 4 + r) * DD + h * DHH + nt * 16 + cidx;
      ctx[off] = oacc[nt][r] * sv;
    }
  }
}

// ---------------- LayerNorm over D=1024 (f32 in-place on d_out) ----------------
__global__ __launch_bounds__(256) void ln_k(
    float* buf, const float* __restrict__ gamma, const float* __restrict__ beta) {
  const int row = blockIdx.x, tid = threadIdx.x;
  const int w = tid >> 6, lane = tid & 63;
  float* x = buf + (size_t)row * DD + tid * 4;
  float4 v = *(const float4*)x;
  float s = v.x + v.y + v.z + v.w;
  float sq = v.x * v.x + v.y * v.y + v.z * v.z + v.w * v.w;
#pragma unroll
  for (int off = 1; off < 64; off <<= 1) {
    s += __shfl_xor(s, off, 64);
    sq += __shfl_xor(sq, off, 64);
  }
  __shared__ float red[8];
  if (lane == 0) { red[w] = s; red[4 + w] = sq; }
  __syncthreads();
  s = red[0] + red[1] + red[2] + red[3];
  sq = red[4] + red[5] + red[6] + red[7];
  const float mu = s * (1.f / 1024.f);
  const float var = sq * (1.f / 1024.f) - mu * mu;
  const float rs = rsqrtf(fmaxf(var, 0.f) + 1e-6f);
  const float4 gr = *(const float4*)(gamma + tid * 4);
  const float4 br = *(const float4*)(beta + tid * 4);
  float4 y;
  y.x = (v.x - mu) * rs * gr.x + br.x;
  y.y = (v.y - mu) * rs * gr.y + br.y;
  y.z = (v.z - mu) * rs * gr.z + br.z;
  y.w = (v.w - mu) * rs * gr.w + br.w;
  *(float4*)x = y;
}

extern "C" void kernel_launch(void* const* d_in, const int* in_sizes, int n_in,
                              void* d_out, int out_size, void* d_ws, size_t ws_size,
                              hipStream_t stream) {
  const float* para    = (const float*)d_in[0];
  const float* cluster = (const float*)d_in[1];
  const float* edge    = (const float*)d_in[2];
  const float* Wq      = (const float*)d_in[3];
  const float* bq      = (const float*)d_in[4];
  const float* Wk      = (const float*)d_in[5];
  const float* bk      = (const float*)d_in[6];
  const float* Wv      = (const float*)d_in[7];
  const float* bv      = (const float*)d_in[8];
  const float* gamma   = (const float*)d_in[9];
  const float* beta    = (const float*)d_in[10];
  float* out = (float*)d_out;   // ctx lives here (attn writes f32, LN in-place)

  // bf16 workspace: 25M u16 = 50 MB
  u16* WqT = (u16*)d_ws;                        // 1M
  u16* WkT = WqT + (size_t)1024 * 1024;         // 1M
  u16* WvT = WkT + (size_t)1024 * 1024;         // 1M
  u16* Qb  = WvT + (size_t)1024 * 1024;         // 8M
  u16* Kp  = Qb  + (size_t)8192 * 1024;         // 2M  [b][h][c][64]
  u16* Vt  = Kp  + (size_t)2048 * 1024;         // 2M  [b][h][d][512]
  u16* Ap  = Vt  + (size_t)2048 * 1024;         // 8M (para bf16)
  u16* Ac  = Ap  + (size_t)8192 * 1024;         // 2M (cluster bf16)

  cast_k<<<dim3(2048), dim3(256), 0, stream>>>(para, cluster, Ap, Ac);
  transpose3_k<<<dim3(32, 32, 3), dim3(32, 32), 0, stream>>>(Wq, Wk, Wv, WqT, WkT, WvT);
  qkv_gemm3<<<dim3(96, 8), dim3(256), 0, stream>>>(Ap, Ac, WqT, WkT, WvT,
                                                   bq, bk, bv, Qb, Kp, Vt);
  attn_k4<<<dim3(PP / 128, HH, BB), dim3(512), 0, stream>>>(Qb, Kp, Vt, edge, out);
  ln_k<<<dim3(BB * PP), dim3(256), 0, stream>>>(out, gamma, beta);
}

// Round 2
// 226.414 us; speedup vs baseline: 1.3419x; 1.0842x over previous
//
#include <hip/hip_runtime.h>

#define BB 4
#define PP 2048
#define CCLUS 512
#define DD 1024
#define HH 16
#define DHH 64

typedef __attribute__((ext_vector_type(8))) short short8;
typedef __attribute__((ext_vector_type(4))) float floatx4;
typedef unsigned short u16;
typedef unsigned int u32;
typedef unsigned long long u64;

__device__ __forceinline__ float bf2f(u16 u) {
  union { u32 i; float f; } v; v.i = ((u32)u) << 16; return v.f;
}
__device__ __forceinline__ u16 f2bf(float f) {
  union { float f; u32 i; } v; v.f = f;
  u32 x = v.i;
  return (u16)((x + 0x7fffu + ((x >> 16) & 1u)) >> 16);  // RNE
}

__device__ __forceinline__ floatx4 mfma16(short8 a, short8 b, floatx4 c) {
  return __builtin_amdgcn_mfma_f32_16x16x32_bf16(a, b, c, 0, 0, 0);
}

// async global->LDS, 16B/lane; LDS dest = wave-uniform base + lane*16 (m97)
__device__ __forceinline__ void gload_lds16(const u16* g, u16* l) {
  __builtin_amdgcn_global_load_lds(
      (const __attribute__((address_space(1))) u32*)g,
      (__attribute__((address_space(3))) u32*)l, 16, 0, 0);
}

// ---------------- f32 -> bf16 cast for para & cluster ----------------
__global__ __launch_bounds__(256) void cast_k(
    const float* __restrict__ para, const float* __restrict__ cluster,
    u16* __restrict__ Ap, u16* __restrict__ Ac) {
  const int NP4 = (BB * PP * DD) / 4;
  const int NC4 = (BB * CCLUS * DD) / 4;
  const int stride = gridDim.x * blockDim.x;
  for (int i = blockIdx.x * blockDim.x + threadIdx.x; i < NP4 + NC4; i += stride) {
    const float* src; u16* dst; int j;
    if (i < NP4) { src = para; dst = Ap; j = i; }
    else         { src = cluster; dst = Ac; j = i - NP4; }
    const float4 v = *(const float4*)(src + (size_t)j * 4);
    u64 p = (u64)f2bf(v.x) | ((u64)f2bf(v.y) << 16) | ((u64)f2bf(v.z) << 32) |
            ((u64)f2bf(v.w) << 48);
    *(u64*)(dst + (size_t)j * 4) = p;
  }
}

// ---------------- transpose+cast Wq/Wk/Wv (1024x1024 f32 -> bf16^T) ----------------
__global__ __launch_bounds__(1024) void transpose3_k(
    const float* __restrict__ Wq, const float* __restrict__ Wk, const float* __restrict__ Wv,
    u16* __restrict__ WqT, u16* __restrict__ WkT, u16* __restrict__ WvT) {
  __shared__ u16 tile[32][33];
  const int z = blockIdx.z;
  const float* src = (z == 0) ? Wq : (z == 1) ? Wk : Wv;
  u16* dst = (z == 0) ? WqT : (z == 1) ? WkT : WvT;
  int x = blockIdx.x * 32 + threadIdx.x;
  int y = blockIdx.y * 32 + threadIdx.y;
  tile[threadIdx.y][threadIdx.x] = f2bf(src[y * DD + x]);
  __syncthreads();
  x = blockIdx.y * 32 + threadIdx.x;
  y = blockIdx.x * 32 + threadIdx.y;
  dst[y * DD + x] = tile[threadIdx.x][threadIdx.y];
}

// ---------------- fused QKV GEMM (m97 global_load_lds staging) ----------------
// Q -> Qb[b*P+p][1024], scale folds 1/sqrt(DH) AND log2(e) (attn uses 2^x)
// K -> Kp[b][h][c][64]   (per-head row-major; 16-lane 32B segments, coalesced-ok)
// V -> Vb[b*512+c][1024] (row-major coalesced; transposed later by vt_k)
// packed grid.x=96: [0,64)=Q, [64,80)=K, [80,96)=V.
__global__ __launch_bounds__(256) void qkv_gemm3(
    const u16* __restrict__ Ap, const u16* __restrict__ Ac,
    const u16* __restrict__ WqT, const u16* __restrict__ WkT, const u16* __restrict__ WvT,
    const float* __restrict__ bq, const float* __restrict__ bk, const float* __restrict__ bv,
    u16* __restrict__ Qb, u16* __restrict__ Kp, u16* __restrict__ Vb) {
  const int bx = blockIdx.x;
  const u16* A; const u16* BT; const float* bias; u16* Cout; float scale; int mt, mode;
  if (bx < 64)      { A = Ap; BT = WqT; bias = bq; Cout = Qb; scale = 0.18033688f; mt = bx;      mode = 0; }
  else if (bx < 80) { A = Ac; BT = WkT; bias = bk; Cout = 0;  scale = 1.0f;        mt = bx - 64; mode = 1; }
  else              { A = Ac; BT = WvT; bias = bv; Cout = Vb; scale = 1.0f;        mt = bx - 80; mode = 2; }

  __shared__ __align__(16) u16 As[128 * 32];
  __shared__ __align__(16) u16 Bs[128 * 32];

  const int tid = threadIdx.x;
  const int w = tid >> 6, lane = tid & 63, quad = lane >> 4, cidx = lane & 15;
  const int wy = w >> 1, wx = w & 1;
  const int m0 = mt * 128, n0 = blockIdx.y * 128;

  floatx4 acc[4][4];
#pragma unroll
  for (int i = 0; i < 4; i++)
#pragma unroll
    for (int j = 0; j < 4; j++) acc[i][j] = (floatx4){0.f, 0.f, 0.f, 0.f};

  const int row0 = tid >> 2, kc0 = tid & 3;
  const int offG0 = row0 * 1024 + kc0 * 8;
  const int offG1 = (row0 + 64) * 1024 + kc0 * 8;
  u16* ldsA0 = As + (size_t)(w * 64) * 8;
  u16* ldsA1 = As + (size_t)(w * 64 + 256) * 8;
  u16* ldsB0 = Bs + (size_t)(w * 64) * 8;
  u16* ldsB1 = Bs + (size_t)(w * 64 + 256) * 8;

  const u16* Abase = A + (size_t)m0 * 1024;
  const u16* Bbase = BT + (size_t)n0 * 1024;

  for (int kt = 0; kt < 32; kt++) {
    const u16* Ak = Abase + kt * 32;
    const u16* Bk = Bbase + kt * 32;
    gload_lds16(Ak + offG0, ldsA0);
    gload_lds16(Ak + offG1, ldsA1);
    gload_lds16(Bk + offG0, ldsB0);
    gload_lds16(Bk + offG1, ldsB1);
    __syncthreads();

    short8 af[4], bfr[4];
#pragma unroll
    for (int i = 0; i < 4; i++) {
      int ra = wy * 64 + i * 16 + cidx;
      af[i] = *(const short8*)&As[ra * 32 + quad * 8];
      int rb = wx * 64 + i * 16 + cidx;
      bfr[i] = *(const short8*)&Bs[rb * 32 + quad * 8];
    }
#pragma unroll
    for (int mi = 0; mi < 4; mi++)
#pragma unroll
      for (int ni = 0; ni < 4; ni++)
        acc[mi][ni] = mfma16(af[mi], bfr[ni], acc[mi][ni]);
    __syncthreads();
  }

#pragma unroll
  for (int ni = 0; ni < 4; ni++) {
    const int ncol = n0 + wx * 64 + ni * 16 + cidx;
    const float bvv = bias[ncol];
#pragma unroll
    for (int mi = 0; mi < 4; mi++) {
      const int mrow = m0 + wy * 64 + mi * 16 + quad * 4;
      if (mode == 1) {
        const int hh2 = ncol >> 6, dh = ncol & 63;
#pragma unroll
        for (int r = 0; r < 4; r++) {
          const int row = mrow + r;
          const int bb = row >> 9, c = row & 511;
          Kp[((size_t)(bb * HH + hh2) * CCLUS + c) * DHH + dh] = f2bf(acc[mi][ni][r] + bvv);
        }
      } else {
#pragma unroll
        for (int r = 0; r < 4; r++) {
          float v = (acc[mi][ni][r] + bvv) * scale;
          Cout[(size_t)(mrow + r) * 1024 + ncol] = f2bf(v);
        }
      }
    }
  }
}

// ---------------- V transpose: Vb[b*512+c][1024] -> Vt[(b*16+h)*64+d][512] ----------------
__global__ __launch_bounds__(256) void vt_k(
    const u16* __restrict__ Vb, u16* __restrict__ Vt) {
  __shared__ u16 t[64][72];
  const int ct = blockIdx.x;              // c-tile of 64 (8 tiles)
  const int bh = blockIdx.y;              // b*16+h (64)
  const int b = bh >> 4, h = bh & 15;
  const int tid = threadIdx.x;
#pragma unroll
  for (int pass = 0; pass < 2; pass++) {
    int idx = pass * 256 + tid;           // 0..511
    int c = idx >> 3, d0 = (idx & 7) * 8;
    short8 v = *(const short8*)&Vb[(size_t)(b * 512 + ct * 64 + c) * 1024 + h * 64 + d0];
    *(short8*)&t[c][d0] = v;
  }
  __syncthreads();
#pragma unroll
  for (int pass = 0; pass < 2; pass++) {
    int idx = pass * 256 + tid;
    int d = idx >> 3, c0 = (idx & 7) * 8;
    short8 o;
#pragma unroll
    for (int j = 0; j < 8; j++) ((u16*)&o)[j] = t[c0 + j][d];
    *(short8*)&Vt[((size_t)(bh) * 64 + d) * 512 + ct * 64 + c0] = o;
  }
}

// ---------------- fused masked attention v5: permlane P-exchange, LDS 32KB ----------------
// 8 waves x 512 threads; block = 128 p-rows, wave = 16 p-rows.
// K[64c][64d], V^T[64d][64c] double-buffered, XOR-swizzled LDS (T2+T3-min).
// S^T = K.Q^T per 16-c tile; lane owns S^T[c=16t+4q+r][p=cidx]. P->bf16 via
// v_cvt_pk_bf16_f32; quad exchange to PV A-layout via permlane32/16_swap (T12):
//   W0,W2 = pl16(pl32(A0,A1)); W1,W3 = pl16(pl32(B0,B1))
// No attnS LDS -> 32KB total -> 4 blocks/CU (32 waves, occupancy cap).
// Q was pre-scaled by log2(e)/8 so exp is a single v_exp_f32 (2^x).
__global__ __launch_bounds__(512, 8) void attn_k5(
    const u16* __restrict__ Qb, const u16* __restrict__ Kp, const u16* __restrict__ Vt,
    const float* __restrict__ edge, float* __restrict__ ctx) {
  const int b = blockIdx.z, h = blockIdx.y, p0 = blockIdx.x * 128;
  const int tid = threadIdx.x;
  const int w = tid >> 6, lane = tid & 63, quad = lane >> 4, cidx = lane & 15;

  __shared__ __align__(16) u16 Ks[2][64 * 64];      // [c][d] swizzled, 8KB each
  __shared__ __align__(16) u16 Vs[2][64 * 64];      // [d][c] swizzled, 8KB each

  const u16* __restrict__ Kbh = Kp + (size_t)(b * HH + h) * CCLUS * DHH;
  const u16* __restrict__ Vbh = Vt + (size_t)(b * HH + h) * DHH * CCLUS;

  // Q frags (B-operand: n=cidx -> p row, k=quad*8+j), loaded once
  const int prow = p0 + w * 16 + cidx;
  const u16* qg = Qb + (size_t)(b * PP + prow) * DD + h * DHH + quad * 8;
  const short8 qf0 = *(const short8*)qg;
  const short8 qf1 = *(const short8*)(qg + 32);
  const float* Erow = edge + (size_t)(b * PP + prow) * CCLUS;

  float srow = 0.f;
  floatx4 oacc[4];
#pragma unroll
  for (int nt = 0; nt < 4; nt++) oacc[nt] = (floatx4){0.f, 0.f, 0.f, 0.f};

  // staging geometry: slot=tid (512 slots x 16B = one 8KB buffer)
  const int srow_i = tid >> 3;                        // row 0..63
  const int sc = ((tid & 7) ^ (srow_i & 7)) << 3;     // inverse-swizzled src col (u16)
  const int ldsoff = w * 512;                         // wave window (u16)

  auto STAGE = [&](int cc, int bufi) {
    const u16* kg = Kbh + (size_t)cc * 64 * DHH;
    const u16* vg = Vbh + cc * 64;
    gload_lds16(kg + (size_t)srow_i * DHH + sc, &Ks[bufi][ldsoff]);
    gload_lds16(vg + (size_t)srow_i * CCLUS + sc, &Vs[bufi][ldsoff]);
  };

  STAGE(0, 0);
  __syncthreads();

  const int swz = (cidx & 7) << 3;  // read-side XOR (u16 units), row&7 == cidx&7

  for (int cc = 0; cc < 8; cc++) {
    const int bufi = cc & 1;
    if (cc < 7) STAGE(cc + 1, bufi ^ 1);  // async prefetch into other buffer
    const u16* __restrict__ KsB = &Ks[bufi][0];
    const u16* __restrict__ VsB = &Vs[bufi][0];

#pragma unroll
    for (int ks = 0; ks < 2; ks++) {
      u32 pa[2], pb[2];
#pragma unroll
      for (int tt = 0; tt < 2; tt++) {
        const int t = ks * 2 + tt;
        const int krow = (t * 16 + cidx) * 64;
        const short8 kf0 = *(const short8*)&KsB[krow + ((quad * 8) ^ swz)];
        const short8 kf1 = *(const short8*)&KsB[krow + ((32 + quad * 8) ^ swz)];
        floatx4 s4 = (floatx4){0.f, 0.f, 0.f, 0.f};
        __builtin_amdgcn_s_setprio(1);
        s4 = mfma16(kf0, qf0, s4);
        s4 = mfma16(kf1, qf1, s4);
        __builtin_amdgcn_s_setprio(0);
        // lane owns S^T[c = cc*64+t*16+quad*4+r][p = prow]
        const int ce = cc * 64 + t * 16 + quad * 4;
        const float4 e4 = *(const float4*)(Erow + ce);
        float E[4];
#pragma unroll
        for (int r = 0; r < 4; r++) {
          const float e = (&e4.x)[r];
          float x = fminf(s4[r], 21.6f);       // 2^21.6 ~ e^15 cap
          float ex;
          asm("v_exp_f32 %0, %1\n\ts_nop 0" : "=v"(ex) : "v"(x));  // 2^x, +trans hazard pad
          ex = (e > 0.f) ? ex : 0.f;
          srow += ex;
          E[r] = ex * e;
        }
        asm("v_cvt_pk_bf16_f32 %0, %1, %2" : "=v"(pa[tt]) : "v"(E[0]), "v"(E[1]));
        asm("v_cvt_pk_bf16_f32 %0, %1, %2" : "=v"(pb[tt]) : "v"(E[2]), "v"(E[3]));
      }
      // quad exchange: target lane (cidx,q') word w <- tile 2ks+(q'>>1),
      // qsrc = 2(q'&1)+(w>>1), pair (w&1).  pl32 then pl16 realizes it exactly.
      asm("v_permlane32_swap_b32 %0, %1" : "+v"(pa[0]), "+v"(pa[1]));
      asm("v_permlane16_swap_b32 %0, %1" : "+v"(pa[0]), "+v"(pa[1]));
      asm("v_permlane32_swap_b32 %0, %1" : "+v"(pb[0]), "+v"(pb[1]));
      asm("v_permlane16_swap_b32 %0, %1" : "+v"(pb[0]), "+v"(pb[1]));
      union { u32 u[4]; short8 s; } af;
      af.u[0] = pa[0]; af.u[1] = pb[0]; af.u[2] = pa[1]; af.u[3] = pb[1];
      // PV: A = P[p=cidx][c=32ks+8q+j], B = V^T from swizzled LDS
      __builtin_amdgcn_s_setprio(1);
#pragma unroll
      for (int nt = 0; nt < 4; nt++) {
        const short8 bfr =
            *(const short8*)&VsB[(nt * 16 + cidx) * 64 + ((ks * 32 + quad * 8) ^ swz)];
        oacc[nt] = mfma16(af.s, bfr, oacc[nt]);
      }
      __builtin_amdgcn_s_setprio(0);
    }
    __syncthreads();  // drains prefetch (vmcnt) + protects buffer reuse
  }

  // reduce srow across quads (lane^16, lane^32 hold same p, disjoint c)
  srow += __shfl_xor(srow, 16, 64);
  srow += __shfl_xor(srow, 32, 64);
  const float sinv = (srow > 0.f) ? 1.0f / srow : 0.f;

#pragma unroll
  for (int r = 0; r < 4; r++) {
    const float sv = __shfl(sinv, quad * 4 + r, 16);  // sinv of p-local quad*4+r
#pragma unroll
    for (int nt = 0; nt < 4; nt++) {
      const size_t off =
          (size_t)(b * PP + p0 + w * 16 + quad * 4 + r) * DD + h * DHH + nt * 16 + cidx;
      ctx[off] = oacc[nt][r] * sv;
    }
  }
}

// ---------------- LayerNorm over D=1024 (f32 in-place on d_out) ----------------
__global__ __launch_bounds__(256) void ln_k(
    float* buf, const float* __restrict__ gamma, const float* __restrict__ beta) {
  const int row = blockIdx.x, tid = threadIdx.x;
  const int w = tid >> 6, lane = tid & 63;
  float* x = buf + (size_t)row * DD + tid * 4;
  float4 v = *(const float4*)x;
  float s = v.x + v.y + v.z + v.w;
  float sq = v.x * v.x + v.y * v.y + v.z * v.z + v.w * v.w;
#pragma unroll
  for (int off = 1; off < 64; off <<= 1) {
    s += __shfl_xor(s, off, 64);
    sq += __shfl_xor(sq, off, 64);
  }
  __shared__ float red[8];
  if (lane == 0) { red[w] = s; red[4 + w] = sq; }
  __syncthreads();
  s = red[0] + red[1] + red[2] + red[3];
  sq = red[4] + red[5] + red[6] + red[7];
  const float mu = s * (1.f / 1024.f);
  const float var = sq * (1.f / 1024.f) - mu * mu;
  const float rs = rsqrtf(fmaxf(var, 0.f) + 1e-6f);
  const float4 gr = *(const float4*)(gamma + tid * 4);
  const float4 br = *(const float4*)(beta + tid * 4);
  float4 y;
  y.x = (v.x - mu) * rs * gr.x + br.x;
  y.y = (v.y - mu) * rs * gr.y + br.y;
  y.z = (v.z - mu) * rs * gr.z + br.z;
  y.w = (v.w - mu) * rs * gr.w + br.w;
  *(float4*)x = y;
}

extern "C" void kernel_launch(void* const* d_in, const int* in_sizes, int n_in,
                              void* d_out, int out_size, void* d_ws, size_t ws_size,
                              hipStream_t stream) {
  const float* para    = (const float*)d_in[0];
  const float* cluster = (const float*)d_in[1];
  const float* edge    = (const float*)d_in[2];
  const float* Wq      = (const float*)d_in[3];
  const float* bq      = (const float*)d_in[4];
  const float* Wk      = (const float*)d_in[5];
  const float* bk      = (const float*)d_in[6];
  const float* Wv      = (const float*)d_in[7];
  const float* bv      = (const float*)d_in[8];
  const float* gamma   = (const float*)d_in[9];
  const float* beta    = (const float*)d_in[10];
  float* out = (float*)d_out;   // ctx lives here (attn writes f32, LN in-place)

  // bf16 workspace: 27M u16 = 54 MB
  u16* WqT = (u16*)d_ws;                        // 1M
  u16* WkT = WqT + (size_t)1024 * 1024;         // 1M
  u16* WvT = WkT + (size_t)1024 * 1024;         // 1M
  u16* Qb  = WvT + (size_t)1024 * 1024;         // 8M
  u16* Kp  = Qb  + (size_t)8192 * 1024;         // 2M  [b][h][c][64]
  u16* Vt  = Kp  + (size_t)2048 * 1024;         // 2M  [b][h][d][512]
  u16* Ap  = Vt  + (size_t)2048 * 1024;         // 8M (para bf16)
  u16* Ac  = Ap  + (size_t)8192 * 1024;         // 2M (cluster bf16)
  u16* Vb  = Ac  + (size_t)2048 * 1024;         // 2M (V row-major staging)

  cast_k<<<dim3(2048), dim3(256), 0, stream>>>(para, cluster, Ap, Ac);
  transpose3_k<<<dim3(32, 32, 3), dim3(32, 32), 0, stream>>>(Wq, Wk, Wv, WqT, WkT, WvT);
  qkv_gemm3<<<dim3(96, 8), dim3(256), 0, stream>>>(Ap, Ac, WqT, WkT, WvT,
                                                   bq, bk, bv, Qb, Kp, Vb);
  vt_k<<<dim3(8, 64), dim3(256), 0, stream>>>(Vb, Vt);
  attn_k5<<<dim3(PP / 128, HH, BB), dim3(512), 0, stream>>>(Qb, Kp, Vt, edge, out);
  ln_k<<<dim3(BB * PP), dim3(256), 0, stream>>>(out, gamma, beta);
}